// Round 1
// baseline (1814.852 us; speedup 1.0000x reference)
//
#include <hip/hip_runtime.h>

#define DIM 512
#define BM  128
#define BK  128
#define DT  32
#define LDSX (BM + 4)   // 132 floats: keeps d-row starts 16B-aligned, spreads banks

// ---------------- e_sq: one wave per code ----------------
__global__ __launch_bounds__(256)
void esq_kernel(const float* __restrict__ embed, float* __restrict__ e_sq, int K) {
    int wave = (blockIdx.x * blockDim.x + threadIdx.x) >> 6;
    int lane = threadIdx.x & 63;
    if (wave >= K) return;
    const float* row = embed + (size_t)wave * DIM;
    float s = 0.f;
#pragma unroll
    for (int j = 0; j < DIM / 64; ++j) { float v = row[lane + 64 * j]; s += v * v; }
#pragma unroll
    for (int off = 32; off; off >>= 1) s += __shfl_down(s, off, 64);
    if (lane == 0) e_sq[wave] = s;
}

// ---------------- fused GEMM + argmin ----------------
// score(row, c) = e_sq[c] - 2 * dot(x[row], embed[c]);  argmin == reference argmax
__global__ __launch_bounds__(256)
void vq_argmin_kernel(const float* __restrict__ x, const float* __restrict__ embed,
                      const float* __restrict__ e_sq, float* __restrict__ out_idx,
                      int N, int K) {
    __shared__ float xs[DT * LDSX];       // xs[d][row]  (transposed)
    __shared__ float es[DT * LDSX];       // es[d][code] (transposed)
    __shared__ float sval[BM * 17];
    __shared__ int   sidx[BM * 17];

    const int tid = threadIdx.x;
    const int tx  = tid & 15;
    const int ty  = tid >> 4;
    const int r0  = blockIdx.x * BM;

    float best_val[8];
    int   best_idx[8];
#pragma unroll
    for (int i = 0; i < 8; ++i) { best_val[i] = 3.4e38f; best_idx[i] = 0; }

    const int nkt = K / BK;
    for (int kt = 0; kt < nkt; ++kt) {
        float acc[8][8];
#pragma unroll
        for (int i = 0; i < 8; ++i)
#pragma unroll
            for (int j = 0; j < 8; ++j) acc[i][j] = 0.f;

        for (int dt = 0; dt < DIM / DT; ++dt) {
            __syncthreads();   // previous chunk fully consumed
            // stage x tile (128 rows x 32 dims) transposed into xs
#pragma unroll
            for (int k = 0; k < 4; ++k) {
                int l = tid + k * 256;           // 0..1023 float4 slots
                int row = l >> 3;                // 8 float4 per row
                int q = l & 7;
                const float4 v = *(const float4*)(x + (size_t)(r0 + row) * DIM + dt * DT + q * 4);
                xs[(q * 4 + 0) * LDSX + row] = v.x;
                xs[(q * 4 + 1) * LDSX + row] = v.y;
                xs[(q * 4 + 2) * LDSX + row] = v.z;
                xs[(q * 4 + 3) * LDSX + row] = v.w;
            }
            // stage embed tile (128 codes x 32 dims) transposed into es
#pragma unroll
            for (int k = 0; k < 4; ++k) {
                int l = tid + k * 256;
                int row = l >> 3;                // code within tile
                int q = l & 7;
                const float4 v = *(const float4*)(embed + (size_t)(kt * BK + row) * DIM + dt * DT + q * 4);
                es[(q * 4 + 0) * LDSX + row] = v.x;
                es[(q * 4 + 1) * LDSX + row] = v.y;
                es[(q * 4 + 2) * LDSX + row] = v.z;
                es[(q * 4 + 3) * LDSX + row] = v.w;
            }
            __syncthreads();

#pragma unroll
            for (int d = 0; d < DT; ++d) {
                const float4 a0 = *(const float4*)&xs[d * LDSX + 4 * ty];
                const float4 a1 = *(const float4*)&xs[d * LDSX + 4 * ty + 64];
                const float4 b0 = *(const float4*)&es[d * LDSX + 4 * tx];
                const float4 b1 = *(const float4*)&es[d * LDSX + 4 * tx + 64];
                const float a[8] = {a0.x, a0.y, a0.z, a0.w, a1.x, a1.y, a1.z, a1.w};
                const float b[8] = {b0.x, b0.y, b0.z, b0.w, b1.x, b1.y, b1.z, b1.w};
#pragma unroll
                for (int i = 0; i < 8; ++i)
#pragma unroll
                    for (int j = 0; j < 8; ++j)
                        acc[i][j] += a[i] * b[j];
            }
        }

        // epilogue: update per-row best over this 128-code tile (codes ascend with j)
#pragma unroll
        for (int j = 0; j < 8; ++j) {
            const int c = kt * BK + 4 * tx + (j & 3) + 64 * (j >> 2);
            const float eq = e_sq[c];
#pragma unroll
            for (int i = 0; i < 8; ++i) {
                const float s = eq - 2.0f * acc[i][j];
                if (s < best_val[i]) { best_val[i] = s; best_idx[i] = c; }
            }
        }
    }

    // cross-thread reduction: 16 tx candidates per row
    __syncthreads();
#pragma unroll
    for (int i = 0; i < 8; ++i) {
        const int r = 4 * ty + (i & 3) + 64 * (i >> 2);
        sval[r * 17 + tx] = best_val[i];
        sidx[r * 17 + tx] = best_idx[i];
    }
    __syncthreads();
    if (tid < BM) {
        float bv = sval[tid * 17 + 0];
        int   bi = sidx[tid * 17 + 0];
#pragma unroll
        for (int t = 1; t < 16; ++t) {
            const float v  = sval[tid * 17 + t];
            const int   ix = sidx[tid * 17 + t];
            if (v < bv || (v == bv && ix < bi)) { bv = v; bi = ix; }
        }
        out_idx[r0 + tid] = (float)bi;
    }
}

// ---------------- decode gather: quantize = embed[idx] ----------------
__global__ __launch_bounds__(256)
void gather_kernel(const float* __restrict__ embed, const float* __restrict__ idx_f,
                   float* __restrict__ out_q) {
    const int row = blockIdx.x * 2 + (threadIdx.x >> 7);
    const int c   = threadIdx.x & 127;
    const int idx = (int)idx_f[row];
    const float4 v = *(const float4*)(embed + (size_t)idx * DIM + c * 4);
    *(float4*)(out_q + (size_t)row * DIM + c * 4) = v;
}

extern "C" void kernel_launch(void* const* d_in, const int* in_sizes, int n_in,
                              void* d_out, int out_size, void* d_ws, size_t ws_size,
                              hipStream_t stream) {
    const float* x     = (const float*)d_in[0];
    const float* embed = (const float*)d_in[1];
    const int N = in_sizes[0] / DIM;   // 65536
    const int K = in_sizes[1] / DIM;   // 2048

    float* e_sq    = (float*)d_ws;
    float* out_idx = (float*)d_out;
    float* out_q   = (float*)d_out + N;

    esq_kernel<<<(K + 3) / 4, 256, 0, stream>>>(embed, e_sq, K);
    vq_argmin_kernel<<<N / BM, 256, 0, stream>>>(x, embed, e_sq, out_idx, N, K);
    gather_kernel<<<N / 2, 256, 0, stream>>>(embed, out_idx, out_q);
}

// Round 2
// 648.845 us; speedup vs baseline: 2.7971x; 2.7971x over previous
//
#include <hip/hip_runtime.h>

#define DIM 512
#define BM  128
#define BK  128
#define DT  32
#define LDSX (BM + 4)

typedef __attribute__((ext_vector_type(8))) short bf16x8;  // 8 bf16 (4 VGPRs)
typedef __attribute__((ext_vector_type(4))) float f32x4;

// ---------- helpers ----------
__device__ __forceinline__ unsigned short f2bf(float f) {
    unsigned u = __float_as_uint(f);
    return (unsigned short)((u + 0x7fffu + ((u >> 16) & 1u)) >> 16);   // RNE
}
__device__ __forceinline__ float bf2f(unsigned short h) {
    return __uint_as_float(((unsigned)h) << 16);
}
__device__ __forceinline__ void async_cp16(const void* g, void* l) {
    __builtin_amdgcn_global_load_lds(
        (const __attribute__((address_space(1))) unsigned int*)g,
        (__attribute__((address_space(3))) unsigned int*)l, 16, 0, 0);
}

// ---------- e_sq: one wave per code (fp32, matches verify path) ----------
__global__ __launch_bounds__(256)
void esq_kernel(const float* __restrict__ embed, float* __restrict__ e_sq, int K) {
    int wave = (blockIdx.x * blockDim.x + threadIdx.x) >> 6;
    int lane = threadIdx.x & 63;
    if (wave >= K) return;
    const float* row = embed + (size_t)wave * DIM;
    float s = 0.f;
#pragma unroll
    for (int j = 0; j < DIM / 64; ++j) { float v = row[lane + 64 * j]; s += v * v; }
#pragma unroll
    for (int off = 32; off; off >>= 1) s += __shfl_down(s, off, 64);
    if (lane == 0) e_sq[wave] = s;
}

// ---------- split fp32 -> bf16 hi + bf16 residual ----------
__global__ __launch_bounds__(256)
void split_bf16_kernel(const float* __restrict__ src, unsigned short* __restrict__ hi,
                       unsigned short* __restrict__ lo, int n4) {
    int i = blockIdx.x * 256 + threadIdx.x;
    if (i >= n4) return;
    float4 v = ((const float4*)src)[i];
    unsigned short h0 = f2bf(v.x), h1 = f2bf(v.y), h2 = f2bf(v.z), h3 = f2bf(v.w);
    unsigned short l0 = f2bf(v.x - bf2f(h0)), l1 = f2bf(v.y - bf2f(h1));
    unsigned short l2 = f2bf(v.z - bf2f(h2)), l3 = f2bf(v.w - bf2f(h3));
    ((uint2*)hi)[i] = make_uint2((unsigned)h0 | ((unsigned)h1 << 16),
                                 (unsigned)h2 | ((unsigned)h3 << 16));
    ((uint2*)lo)[i] = make_uint2((unsigned)l0 | ((unsigned)l1 << 16),
                                 (unsigned)l2 | ((unsigned)l3 << 16));
}

// ---------- MFMA GEMM (3-term split-bf16) + per-row approx top-2 ----------
// score(row,c) = e_sq[c] - 2*dot(x[row],embed[c]); dot ~= xh*eh + xh*el + xl*eh
__global__ __launch_bounds__(256, 2)
void vq_mfma_kernel(const unsigned short* __restrict__ xh_g,
                    const unsigned short* __restrict__ xl_g,
                    const unsigned short* __restrict__ eh_g,
                    const unsigned short* __restrict__ el_g,
                    const float* __restrict__ e_sq,
                    int* __restrict__ cand, int K) {
    // phase 1: four 128x64-bf16 tiles (16 KB each, no padding, XOR-swizzled)
    // phase 2 (after barrier, reuse): rv[128][65] f32 + ri[128][65] i32
    __shared__ __align__(16) char smem[66560];
    unsigned short* xh_l = (unsigned short*)smem;
    unsigned short* xl_l = xh_l + 8192;
    unsigned short* eh_l = xh_l + 16384;
    unsigned short* el_l = xh_l + 24576;

    const int tid  = threadIdx.x;
    const int w    = tid >> 6, lane = tid & 63;
    const int wm   = w & 1,    wn   = w >> 1;
    const int quad = lane >> 4, l15 = lane & 15;
    const int r0   = blockIdx.x * 128;

    float bv1[16], bv2[16];
    int   bi1[16], bi2[16];
#pragma unroll
    for (int i = 0; i < 16; ++i) { bv1[i] = bv2[i] = 3.4e38f; bi1[i] = bi2[i] = 0; }

    // staging slot descriptors: slot s = w*256 + t*64 + lane; item = s>>3, chunk = s&7
    int item_[4], chs_[4];
#pragma unroll
    for (int t = 0; t < 4; ++t) {
        int s = w * 256 + t * 64 + lane;
        item_[t] = s >> 3;
        chs_[t]  = (s & 7) ^ (item_[t] & 7);   // XOR swizzle: LDS[item][ch] <- global ch^(item&7)
    }

    const int NT = K / 128;
    for (int kt = 0; kt < NT; ++kt) {
        f32x4 acc[4][4];
#pragma unroll
        for (int a = 0; a < 4; ++a)
#pragma unroll
            for (int b = 0; b < 4; ++b)
#pragma unroll
                for (int r = 0; r < 4; ++r) acc[a][b][r] = 0.f;

        for (int dt = 0; dt < 8; ++dt) {
            __syncthreads();
#pragma unroll
            for (int t = 0; t < 4; ++t) {
                const int item = item_[t], chs = chs_[t];
                const int ldso = (w * 256 + t * 64) * 8;  // ushort units (lane adds 16B)
                const size_t gx = (size_t)(r0 + item) * DIM + dt * 64 + chs * 8;
                const size_t ge = (size_t)(kt * 128 + item) * DIM + dt * 64 + chs * 8;
                async_cp16(xh_g + gx, xh_l + ldso);
                async_cp16(xl_g + gx, xl_l + ldso);
                async_cp16(eh_g + ge, eh_l + ldso);
                async_cp16(el_g + ge, el_l + ldso);
            }
            __syncthreads();
#pragma unroll
            for (int q = 0; q < 2; ++q) {
                const int ch = (q * 4 + quad) ^ (lane & 7);
                bf16x8 ah[4], al[4], bh[4], bl[4];
#pragma unroll
                for (int mt = 0; mt < 4; ++mt) {
                    const int off = (wm * 64 + mt * 16 + l15) * 64 + ch * 8;
                    ah[mt] = *(const bf16x8*)(xh_l + off);
                    al[mt] = *(const bf16x8*)(xl_l + off);
                }
#pragma unroll
                for (int nt = 0; nt < 4; ++nt) {
                    const int off = (wn * 64 + nt * 16 + l15) * 64 + ch * 8;
                    bh[nt] = *(const bf16x8*)(eh_l + off);
                    bl[nt] = *(const bf16x8*)(el_l + off);
                }
#pragma unroll
                for (int mt = 0; mt < 4; ++mt)
#pragma unroll
                    for (int nt = 0; nt < 4; ++nt) {
                        acc[mt][nt] = __builtin_amdgcn_mfma_f32_16x16x32_bf16(ah[mt], bh[nt], acc[mt][nt], 0, 0, 0);
                        acc[mt][nt] = __builtin_amdgcn_mfma_f32_16x16x32_bf16(ah[mt], bl[nt], acc[mt][nt], 0, 0, 0);
                        acc[mt][nt] = __builtin_amdgcn_mfma_f32_16x16x32_bf16(al[mt], bh[nt], acc[mt][nt], 0, 0, 0);
                    }
            }
        }
        // epilogue: scores for this 128-code tile; update per-lane per-row top-2
#pragma unroll
        for (int nt = 0; nt < 4; ++nt) {
            const int c = kt * 128 + wn * 64 + nt * 16 + l15;
            const float eq = e_sq[c];
#pragma unroll
            for (int mt = 0; mt < 4; ++mt)
#pragma unroll
                for (int r = 0; r < 4; ++r) {
                    const float v = fmaf(-2.0f, acc[mt][nt][r], eq);
                    const int s = mt * 4 + r;
                    const bool lt1 = v < bv1[s];
                    const bool lt2 = v < bv2[s];
                    bv2[s] = lt1 ? bv1[s] : (lt2 ? v : bv2[s]);
                    bi2[s] = lt1 ? bi1[s] : (lt2 ? c : bi2[s]);
                    bv1[s] = lt1 ? v : bv1[s];
                    bi1[s] = lt1 ? c : bi1[s];
                }
        }
    }

    // block-level reduction of top-2 over the 32 lanes covering each row
    __syncthreads();
    float* rv = (float*)smem;
    int*   ri = (int*)(smem + 33280);
#pragma unroll
    for (int mt = 0; mt < 4; ++mt)
#pragma unroll
        for (int r = 0; r < 4; ++r) {
            const int m = wm * 64 + mt * 16 + quad * 4 + r;
            const int base = m * 65 + wn * 32 + l15 * 2;
            const int s = mt * 4 + r;
            rv[base] = bv1[s]; ri[base] = bi1[s];
            rv[base + 1] = bv2[s]; ri[base + 1] = bi2[s];
        }
    __syncthreads();
    if (tid < 128) {
        float b1 = 3.4e38f, b2 = 3.4e38f;
        int i1 = 0, i2 = 1;
#pragma unroll 4
        for (int e = 0; e < 64; ++e) {
            const float v = rv[tid * 65 + e];
            const int   c = ri[tid * 65 + e];
            const bool t1 = (v < b1) || (v == b1 && c < i1);
            const bool t2 = (v < b2) || (v == b2 && c < i2);
            b2 = t1 ? b1 : (t2 ? v : b2);
            i2 = t1 ? i1 : (t2 ? c : i2);
            b1 = t1 ? v : b1;
            i1 = t1 ? c : i1;
        }
        cand[(r0 + tid) * 2]     = i1;
        cand[(r0 + tid) * 2 + 1] = i2;
    }
}

// ---------- exact fp32 re-score of the 2 candidates + fused decode gather ----------
__global__ __launch_bounds__(256)
void verify_gather_kernel(const float* __restrict__ x, const float* __restrict__ embed,
                          const float* __restrict__ e_sq, const int* __restrict__ cand,
                          float* __restrict__ out_idx, float* __restrict__ out_q) {
    const int row  = blockIdx.x * 4 + (threadIdx.x >> 6);
    const int lane = threadIdx.x & 63;
    const int c1 = cand[row * 2], c2 = cand[row * 2 + 1];
    const float* xr = x + (size_t)row * DIM;
    const float* e1 = embed + (size_t)c1 * DIM;
    const float* e2 = embed + (size_t)c2 * DIM;
    float d1 = 0.f, d2 = 0.f, e1v[8], e2v[8];
#pragma unroll
    for (int j = 0; j < 8; ++j) {
        const float xv = xr[lane + 64 * j];
        e1v[j] = e1[lane + 64 * j];
        e2v[j] = e2[lane + 64 * j];
        d1 += xv * e1v[j];
        d2 += xv * e2v[j];
    }
#pragma unroll
    for (int off = 32; off; off >>= 1) {
        d1 += __shfl_xor(d1, off, 64);
        d2 += __shfl_xor(d2, off, 64);
    }
    const float s1 = e_sq[c1] - 2.f * d1;
    const float s2 = e_sq[c2] - 2.f * d2;
    const bool win2 = (s2 < s1) || (s2 == s1 && c2 < c1);
    if (lane == 0) out_idx[row] = (float)(win2 ? c2 : c1);
    float* oq = out_q + (size_t)row * DIM;
#pragma unroll
    for (int j = 0; j < 8; ++j) oq[lane + 64 * j] = win2 ? e2v[j] : e1v[j];
}

// ================= fallback (round-1 fp32 path, used if d_ws too small) =================
__global__ __launch_bounds__(256)
void vq_argmin_kernel(const float* __restrict__ x, const float* __restrict__ embed,
                      const float* __restrict__ e_sq, float* __restrict__ out_idx,
                      int N, int K) {
    __shared__ float xs[DT * LDSX];
    __shared__ float es[DT * LDSX];
    __shared__ float sval[BM * 17];
    __shared__ int   sidx[BM * 17];
    const int tid = threadIdx.x;
    const int tx = tid & 15, ty = tid >> 4;
    const int r0 = blockIdx.x * BM;
    float best_val[8]; int best_idx[8];
#pragma unroll
    for (int i = 0; i < 8; ++i) { best_val[i] = 3.4e38f; best_idx[i] = 0; }
    const int nkt = K / BK;
    for (int kt = 0; kt < nkt; ++kt) {
        float acc[8][8];
#pragma unroll
        for (int i = 0; i < 8; ++i)
#pragma unroll
            for (int j = 0; j < 8; ++j) acc[i][j] = 0.f;
        for (int dt = 0; dt < DIM / DT; ++dt) {
            __syncthreads();
#pragma unroll
            for (int k = 0; k < 4; ++k) {
                int l = tid + k * 256, row = l >> 3, q = l & 7;
                const float4 v = *(const float4*)(x + (size_t)(r0 + row) * DIM + dt * DT + q * 4);
                xs[(q * 4 + 0) * LDSX + row] = v.x; xs[(q * 4 + 1) * LDSX + row] = v.y;
                xs[(q * 4 + 2) * LDSX + row] = v.z; xs[(q * 4 + 3) * LDSX + row] = v.w;
            }
#pragma unroll
            for (int k = 0; k < 4; ++k) {
                int l = tid + k * 256, row = l >> 3, q = l & 7;
                const float4 v = *(const float4*)(embed + (size_t)(kt * BK + row) * DIM + dt * DT + q * 4);
                es[(q * 4 + 0) * LDSX + row] = v.x; es[(q * 4 + 1) * LDSX + row] = v.y;
                es[(q * 4 + 2) * LDSX + row] = v.z; es[(q * 4 + 3) * LDSX + row] = v.w;
            }
            __syncthreads();
#pragma unroll
            for (int d = 0; d < DT; ++d) {
                const float4 a0 = *(const float4*)&xs[d * LDSX + 4 * ty];
                const float4 a1 = *(const float4*)&xs[d * LDSX + 4 * ty + 64];
                const float4 b0 = *(const float4*)&es[d * LDSX + 4 * tx];
                const float4 b1 = *(const float4*)&es[d * LDSX + 4 * tx + 64];
                const float a[8] = {a0.x, a0.y, a0.z, a0.w, a1.x, a1.y, a1.z, a1.w};
                const float b[8] = {b0.x, b0.y, b0.z, b0.w, b1.x, b1.y, b1.z, b1.w};
#pragma unroll
                for (int i = 0; i < 8; ++i)
#pragma unroll
                    for (int j = 0; j < 8; ++j) acc[i][j] += a[i] * b[j];
            }
        }
#pragma unroll
        for (int j = 0; j < 8; ++j) {
            const int c = kt * BK + 4 * tx + (j & 3) + 64 * (j >> 2);
            const float eq = e_sq[c];
#pragma unroll
            for (int i = 0; i < 8; ++i) {
                const float s = eq - 2.0f * acc[i][j];
                if (s < best_val[i]) { best_val[i] = s; best_idx[i] = c; }
            }
        }
    }
    __syncthreads();
#pragma unroll
    for (int i = 0; i < 8; ++i) {
        const int r = 4 * ty + (i & 3) + 64 * (i >> 2);
        sval[r * 17 + tx] = best_val[i]; sidx[r * 17 + tx] = best_idx[i];
    }
    __syncthreads();
    if (tid < BM) {
        float bv = sval[tid * 17 + 0]; int bi = sidx[tid * 17 + 0];
#pragma unroll
        for (int t = 1; t < 16; ++t) {
            const float v = sval[tid * 17 + t]; const int ix = sidx[tid * 17 + t];
            if (v < bv || (v == bv && ix < bi)) { bv = v; bi = ix; }
        }
        out_idx[r0 + tid] = (float)bi;
    }
}

__global__ __launch_bounds__(256)
void gather_kernel(const float* __restrict__ embed, const float* __restrict__ idx_f,
                   float* __restrict__ out_q) {
    const int row = blockIdx.x * 2 + (threadIdx.x >> 7);
    const int c = threadIdx.x & 127;
    const int idx = (int)idx_f[row];
    const float4 v = *(const float4*)(embed + (size_t)idx * DIM + c * 4);
    *(float4*)(out_q + (size_t)row * DIM + c * 4) = v;
}

// ================= launch =================
extern "C" void kernel_launch(void* const* d_in, const int* in_sizes, int n_in,
                              void* d_out, int out_size, void* d_ws, size_t ws_size,
                              hipStream_t stream) {
    const float* x     = (const float*)d_in[0];
    const float* embed = (const float*)d_in[1];
    const int N = in_sizes[0] / DIM;   // 65536
    const int K = in_sizes[1] / DIM;   // 2048

    float* out_idx = (float*)d_out;
    float* out_q   = (float*)d_out + N;
    char* ws = (char*)d_ws;

    const size_t off_esq  = 0;                                   // K*4
    const size_t off_cand = 8192;                                // N*2*4
    const size_t off_eh   = off_cand + (size_t)N * 8;
    const size_t off_el   = off_eh + (size_t)K * DIM * 2;
    const size_t off_xh   = off_el + (size_t)K * DIM * 2;
    const size_t off_xl   = off_xh + (size_t)N * DIM * 2;
    const size_t need     = off_xl + (size_t)N * DIM * 2;

    float* e_sq = (float*)(ws + off_esq);
    esq_kernel<<<(K + 3) / 4, 256, 0, stream>>>(embed, e_sq, K);

    if (ws_size >= need) {
        unsigned short* eh = (unsigned short*)(ws + off_eh);
        unsigned short* el = (unsigned short*)(ws + off_el);
        unsigned short* xh = (unsigned short*)(ws + off_xh);
        unsigned short* xl = (unsigned short*)(ws + off_xl);
        int* cand = (int*)(ws + off_cand);

        split_bf16_kernel<<<(K * DIM / 4 + 255) / 256, 256, 0, stream>>>(embed, eh, el, K * DIM / 4);
        split_bf16_kernel<<<(N * DIM / 4 + 255) / 256, 256, 0, stream>>>(x, xh, xl, N * DIM / 4);
        vq_mfma_kernel<<<N / 128, 256, 0, stream>>>(xh, xl, eh, el, e_sq, cand, K);
        verify_gather_kernel<<<N / 4, 256, 0, stream>>>(x, embed, e_sq, cand, out_idx, out_q);
    } else {
        vq_argmin_kernel<<<N / BM, 256, 0, stream>>>(x, embed, e_sq, out_idx, N, K);
        gather_kernel<<<N / 2, 256, 0, stream>>>(embed, out_idx, out_q);
    }
}

// Round 3
// 477.929 us; speedup vs baseline: 3.7973x; 1.3576x over previous
//
#include <hip/hip_runtime.h>

#define DIM 512
#define BM  128
#define BK  128
#define DT  32
#define LDSX (BM + 4)

typedef __attribute__((ext_vector_type(8))) _Float16 f16x8;
typedef __attribute__((ext_vector_type(4))) _Float16 f16x4;
typedef __attribute__((ext_vector_type(4))) float f32x4;

__device__ __forceinline__ void async_cp16(const void* g, void* l) {
    __builtin_amdgcn_global_load_lds(
        (const __attribute__((address_space(1))) unsigned int*)g,
        (__attribute__((address_space(3))) unsigned int*)l, 16, 0, 0);
}

// ---------- e_sq: one wave per code (fp32, matches verify path) ----------
__global__ __launch_bounds__(256)
void esq_kernel(const float* __restrict__ embed, float* __restrict__ e_sq, int K) {
    int wave = (blockIdx.x * blockDim.x + threadIdx.x) >> 6;
    int lane = threadIdx.x & 63;
    if (wave >= K) return;
    const float* row = embed + (size_t)wave * DIM;
    float s = 0.f;
#pragma unroll
    for (int j = 0; j < DIM / 64; ++j) { float v = row[lane + 64 * j]; s += v * v; }
#pragma unroll
    for (int off = 32; off; off >>= 1) s += __shfl_down(s, off, 64);
    if (lane == 0) e_sq[wave] = s;
}

// ---------- fp32 -> fp16 convert ----------
__global__ __launch_bounds__(256)
void cvt_f16_kernel(const float* __restrict__ src, _Float16* __restrict__ dst, int n4) {
    int i = blockIdx.x * 256 + threadIdx.x;
    if (i >= n4) return;
    float4 v = ((const float4*)src)[i];
    f16x4 h;
    h[0] = (_Float16)v.x; h[1] = (_Float16)v.y; h[2] = (_Float16)v.z; h[3] = (_Float16)v.w;
    ((f16x4*)dst)[i] = h;
}

// ---------- fp16 MFMA GEMM + per-row approx top-4 candidates ----------
// score(row,c) = e_sq[c] - 2*dot(x[row],embed[c]) approximated in fp16
__global__ __launch_bounds__(256, 2)
void vq_f16_kernel(const _Float16* __restrict__ xh_g, const _Float16* __restrict__ eh_g,
                   const float* __restrict__ e_sq, int* __restrict__ cand, int K) {
    // phase 1: two 128x64-f16 tiles (16 KB each, XOR-swizzled, no padding)
    // phase 2 (reuse): rv[128][65] f32 + ri[128][65] i32 = 66560 B
    __shared__ __align__(16) char smem[66560];
    _Float16* xh_l = (_Float16*)smem;
    _Float16* eh_l = xh_l + 8192;

    const int tid  = threadIdx.x;
    const int w    = tid >> 6, lane = tid & 63;
    const int wm   = w & 1,    wn   = w >> 1;
    const int quad = lane >> 4, l15 = lane & 15;
    const int r0   = blockIdx.x * 128;

    float bv1[16], bv2[16];
    int   bi1[16], bi2[16];
#pragma unroll
    for (int i = 0; i < 16; ++i) { bv1[i] = bv2[i] = 3.4e38f; bi1[i] = bi2[i] = 0; }

    int item_[4], chs_[4];
#pragma unroll
    for (int t = 0; t < 4; ++t) {
        int s = w * 256 + t * 64 + lane;
        item_[t] = s >> 3;
        chs_[t]  = (s & 7) ^ (item_[t] & 7);   // LDS[item][p] holds global chunk p^(item&7)
    }

    const int NT = K / 128;
    for (int kt = 0; kt < NT; ++kt) {
        f32x4 acc[4][4];
#pragma unroll
        for (int a = 0; a < 4; ++a)
#pragma unroll
            for (int b = 0; b < 4; ++b)
#pragma unroll
                for (int r = 0; r < 4; ++r) acc[a][b][r] = 0.f;

        for (int dt = 0; dt < 8; ++dt) {
            __syncthreads();
#pragma unroll
            for (int t = 0; t < 4; ++t) {
                const int item = item_[t], chs = chs_[t];
                const int ldso = (w * 256 + t * 64) * 8;   // halfs; lane adds 16 B
                const size_t gx = (size_t)(r0 + item) * DIM + dt * 64 + chs * 8;
                const size_t ge = (size_t)(kt * 128 + item) * DIM + dt * 64 + chs * 8;
                async_cp16(xh_g + gx, xh_l + ldso);
                async_cp16(eh_g + ge, eh_l + ldso);
            }
            __syncthreads();
#pragma unroll
            for (int q = 0; q < 2; ++q) {
                const int ch = (q * 4 + quad) ^ (lane & 7);
                f16x8 ah[4], bh[4];
#pragma unroll
                for (int mt = 0; mt < 4; ++mt)
                    ah[mt] = *(const f16x8*)(xh_l + (wm * 64 + mt * 16 + l15) * 64 + ch * 8);
#pragma unroll
                for (int nt = 0; nt < 4; ++nt)
                    bh[nt] = *(const f16x8*)(eh_l + (wn * 64 + nt * 16 + l15) * 64 + ch * 8);
#pragma unroll
                for (int mt = 0; mt < 4; ++mt)
#pragma unroll
                    for (int nt = 0; nt < 4; ++nt)
                        acc[mt][nt] = __builtin_amdgcn_mfma_f32_16x16x32_f16(ah[mt], bh[nt], acc[mt][nt], 0, 0, 0);
            }
        }
        // per-lane top-2 update over this 128-code tile
#pragma unroll
        for (int nt = 0; nt < 4; ++nt) {
            const int c = kt * 128 + wn * 64 + nt * 16 + l15;
            const float eq = e_sq[c];
#pragma unroll
            for (int mt = 0; mt < 4; ++mt)
#pragma unroll
                for (int r = 0; r < 4; ++r) {
                    const float v = fmaf(-2.0f, acc[mt][nt][r], eq);
                    const int s = mt * 4 + r;
                    const bool lt1 = v < bv1[s];
                    const bool lt2 = v < bv2[s];
                    bv2[s] = lt1 ? bv1[s] : (lt2 ? v : bv2[s]);
                    bi2[s] = lt1 ? bi1[s] : (lt2 ? c : bi2[s]);
                    bv1[s] = lt1 ? v : bv1[s];
                    bi1[s] = lt1 ? c : bi1[s];
                }
        }
    }

    // block reduction: 64 per-lane candidates per row -> top-4
    __syncthreads();
    float* rv = (float*)smem;
    int*   ri = (int*)(smem + 33280);
#pragma unroll
    for (int mt = 0; mt < 4; ++mt)
#pragma unroll
        for (int r = 0; r < 4; ++r) {
            const int m = wm * 64 + mt * 16 + quad * 4 + r;
            const int base = m * 65 + wn * 32 + l15 * 2;
            const int s = mt * 4 + r;
            rv[base] = bv1[s]; ri[base] = bi1[s];
            rv[base + 1] = bv2[s]; ri[base + 1] = bi2[s];
        }
    __syncthreads();
    if (tid < 128) {
        float b[4] = {3.4e38f, 3.4e38f, 3.4e38f, 3.4e38f};
        int   ii[4] = {0, 0, 0, 0};
        for (int e = 0; e < 64; ++e) {
            const float v = rv[tid * 65 + e];
            const int   c = ri[tid * 65 + e];
            if (v < b[3] || (v == b[3] && c < ii[3])) {
                b[3] = v; ii[3] = c;
#pragma unroll
                for (int k = 3; k > 0; --k) {
                    const bool sw = (b[k] < b[k-1]) || (b[k] == b[k-1] && ii[k] < ii[k-1]);
                    const float tv = b[k-1]; const int ti = ii[k-1];
                    b[k-1] = sw ? b[k] : b[k-1]; ii[k-1] = sw ? ii[k] : ii[k-1];
                    b[k] = sw ? tv : b[k];       ii[k] = sw ? ti : ii[k];
                }
            }
        }
#pragma unroll
        for (int k = 0; k < 4; ++k) cand[(size_t)(r0 + tid) * 4 + k] = ii[k];
    }
}

// ---------- exact fp32 re-score of 4 candidates + fused decode gather ----------
__global__ __launch_bounds__(256)
void verify_gather4_kernel(const float* __restrict__ x, const float* __restrict__ embed,
                           const float* __restrict__ e_sq, const int* __restrict__ cand,
                           float* __restrict__ out_idx, float* __restrict__ out_q) {
    const int row  = blockIdx.x * 4 + (threadIdx.x >> 6);
    const int lane = threadIdx.x & 63;
    const float* xr = x + (size_t)row * DIM;
    float xv[8];
#pragma unroll
    for (int j = 0; j < 8; ++j) xv[j] = xr[lane + 64 * j];

    float best = 3.4e38f, bev[8];
    int   bi = 0x7fffffff;
#pragma unroll
    for (int k = 0; k < 4; ++k) {
        const int c = cand[(size_t)row * 4 + k];
        const float* e = embed + (size_t)c * DIM;
        float ev[8], d = 0.f;
#pragma unroll
        for (int j = 0; j < 8; ++j) { ev[j] = e[lane + 64 * j]; d += xv[j] * ev[j]; }
#pragma unroll
        for (int off = 32; off; off >>= 1) d += __shfl_xor(d, off, 64);
        const float s = e_sq[c] - 2.f * d;
        const bool better = (s < best) || (s == best && c < bi);
        best = better ? s : best;
        bi   = better ? c : bi;
#pragma unroll
        for (int j = 0; j < 8; ++j) bev[j] = better ? ev[j] : bev[j];
    }
    if (lane == 0) out_idx[row] = (float)bi;
    float* oq = out_q + (size_t)row * DIM;
#pragma unroll
    for (int j = 0; j < 8; ++j) oq[lane + 64 * j] = bev[j];
}

// ================= fallback (round-1 fp32 path, used if d_ws too small) =================
__global__ __launch_bounds__(256)
void vq_argmin_kernel(const float* __restrict__ x, const float* __restrict__ embed,
                      const float* __restrict__ e_sq, float* __restrict__ out_idx,
                      int N, int K) {
    __shared__ float xs[DT * LDSX];
    __shared__ float es[DT * LDSX];
    __shared__ float sval[BM * 17];
    __shared__ int   sidx[BM * 17];
    const int tid = threadIdx.x;
    const int tx = tid & 15, ty = tid >> 4;
    const int r0 = blockIdx.x * BM;
    float best_val[8]; int best_idx[8];
#pragma unroll
    for (int i = 0; i < 8; ++i) { best_val[i] = 3.4e38f; best_idx[i] = 0; }
    const int nkt = K / BK;
    for (int kt = 0; kt < nkt; ++kt) {
        float acc[8][8];
#pragma unroll
        for (int i = 0; i < 8; ++i)
#pragma unroll
            for (int j = 0; j < 8; ++j) acc[i][j] = 0.f;
        for (int dt = 0; dt < DIM / DT; ++dt) {
            __syncthreads();
#pragma unroll
            for (int k = 0; k < 4; ++k) {
                int l = tid + k * 256, row = l >> 3, q = l & 7;
                const float4 v = *(const float4*)(x + (size_t)(r0 + row) * DIM + dt * DT + q * 4);
                xs[(q * 4 + 0) * LDSX + row] = v.x; xs[(q * 4 + 1) * LDSX + row] = v.y;
                xs[(q * 4 + 2) * LDSX + row] = v.z; xs[(q * 4 + 3) * LDSX + row] = v.w;
            }
#pragma unroll
            for (int k = 0; k < 4; ++k) {
                int l = tid + k * 256, row = l >> 3, q = l & 7;
                const float4 v = *(const float4*)(embed + (size_t)(kt * BK + row) * DIM + dt * DT + q * 4);
                es[(q * 4 + 0) * LDSX + row] = v.x; es[(q * 4 + 1) * LDSX + row] = v.y;
                es[(q * 4 + 2) * LDSX + row] = v.z; es[(q * 4 + 3) * LDSX + row] = v.w;
            }
            __syncthreads();
#pragma unroll
            for (int d = 0; d < DT; ++d) {
                const float4 a0 = *(const float4*)&xs[d * LDSX + 4 * ty];
                const float4 a1 = *(const float4*)&xs[d * LDSX + 4 * ty + 64];
                const float4 b0 = *(const float4*)&es[d * LDSX + 4 * tx];
                const float4 b1 = *(const float4*)&es[d * LDSX + 4 * tx + 64];
                const float a[8] = {a0.x, a0.y, a0.z, a0.w, a1.x, a1.y, a1.z, a1.w};
                const float b[8] = {b0.x, b0.y, b0.z, b0.w, b1.x, b1.y, b1.z, b1.w};
#pragma unroll
                for (int i = 0; i < 8; ++i)
#pragma unroll
                    for (int j = 0; j < 8; ++j) acc[i][j] += a[i] * b[j];
            }
        }
#pragma unroll
        for (int j = 0; j < 8; ++j) {
            const int c = kt * BK + 4 * tx + (j & 3) + 64 * (j >> 2);
            const float eq = e_sq[c];
#pragma unroll
            for (int i = 0; i < 8; ++i) {
                const float s = eq - 2.0f * acc[i][j];
                if (s < best_val[i]) { best_val[i] = s; best_idx[i] = c; }
            }
        }
    }
    __syncthreads();
#pragma unroll
    for (int i = 0; i < 8; ++i) {
        const int r = 4 * ty + (i & 3) + 64 * (i >> 2);
        sval[r * 17 + tx] = best_val[i]; sidx[r * 17 + tx] = best_idx[i];
    }
    __syncthreads();
    if (tid < BM) {
        float bv = sval[tid * 17 + 0]; int bi = sidx[tid * 17 + 0];
#pragma unroll
        for (int t = 1; t < 16; ++t) {
            const float v = sval[tid * 17 + t]; const int ix = sidx[tid * 17 + t];
            if (v < bv || (v == bv && ix < bi)) { bv = v; bi = ix; }
        }
        out_idx[r0 + tid] = (float)bi;
    }
}

__global__ __launch_bounds__(256)
void gather_kernel(const float* __restrict__ embed, const float* __restrict__ idx_f,
                   float* __restrict__ out_q) {
    const int row = blockIdx.x * 2 + (threadIdx.x >> 7);
    const int c = threadIdx.x & 127;
    const int idx = (int)idx_f[row];
    const float4 v = *(const float4*)(embed + (size_t)idx * DIM + c * 4);
    *(float4*)(out_q + (size_t)row * DIM + c * 4) = v;
}

// ================= launch =================
extern "C" void kernel_launch(void* const* d_in, const int* in_sizes, int n_in,
                              void* d_out, int out_size, void* d_ws, size_t ws_size,
                              hipStream_t stream) {
    const float* x     = (const float*)d_in[0];
    const float* embed = (const float*)d_in[1];
    const int N = in_sizes[0] / DIM;   // 65536
    const int K = in_sizes[1] / DIM;   // 2048

    float* out_idx = (float*)d_out;
    float* out_q   = (float*)d_out + N;
    char* ws = (char*)d_ws;

    const size_t off_esq  = 0;                                 // K*4
    const size_t off_cand = 8192;                              // N*4*4
    const size_t off_eh   = off_cand + (size_t)N * 16;         // K*DIM*2
    const size_t off_xh   = off_eh + (size_t)K * DIM * 2;      // N*DIM*2
    const size_t need     = off_xh + (size_t)N * DIM * 2;

    float* e_sq = (float*)(ws + off_esq);
    esq_kernel<<<(K + 3) / 4, 256, 0, stream>>>(embed, e_sq, K);

    if (ws_size >= need) {
        _Float16* eh = (_Float16*)(ws + off_eh);
        _Float16* xh = (_Float16*)(ws + off_xh);
        int* cand = (int*)(ws + off_cand);

        cvt_f16_kernel<<<(K * DIM / 4 + 255) / 256, 256, 0, stream>>>(embed, eh, K * DIM / 4);
        cvt_f16_kernel<<<(N * DIM / 4 + 255) / 256, 256, 0, stream>>>(x, xh, N * DIM / 4);
        vq_f16_kernel<<<N / 128, 256, 0, stream>>>(xh, eh, e_sq, cand, K);
        verify_gather4_kernel<<<N / 4, 256, 0, stream>>>(x, embed, e_sq, cand, out_idx, out_q);
    } else {
        vq_argmin_kernel<<<N / BM, 256, 0, stream>>>(x, embed, e_sq, out_idx, N, K);
        gather_kernel<<<N / 2, 256, 0, stream>>>(embed, out_idx, out_q);
    }
}